// Round 7
// baseline (813.711 us; speedup 1.0000x reference)
//
#include <hip/hip_runtime.h>

typedef _Float16 f16x8 __attribute__((ext_vector_type(8)));
typedef float    f32x4 __attribute__((ext_vector_type(4)));

constexpr int Nn = 32, Cc = 256, HW = 1024, Mm = 2000, Tt = 32768;
constexpr int TB = 64;        // tokens per block (2 token-pairs x 32)
constexpr int XROW = 264;     // X row stride (f16): 528 B rows, 16B-aligned rows
constexpr int YROW = 257;     // y accum row stride (fp32)
constexpr int LCAP = 768;     // candidate cap (expected ~436/block; validated R4-R6)
constexpr int NT = 32;        // M tiles of 64 rows (31 full + 16-row tail)
constexpr float LAMBDA = 0.0025f;
constexpr float PLO = LAMBDA * (1.0f - 3e-3f);   // borderline window (covers GEMM noise + Z regroup)
constexpr float PHI = LAMBDA * (1.0f + 3e-3f);
constexpr float ECUT = 4.8f;  // candidate cut (per-logit e bits unchanged -> same set)
constexpr float SCL = 4096.0f, ISCL = 1.0f / 4096.0f;

__global__ void wcvt_kernel(const float* __restrict__ w,
                            _Float16* __restrict__ whi, _Float16* __restrict__ wlo) {
  int i = blockIdx.x * 256 + threadIdx.x;
  if (i < Mm * Cc) {
    float v = w[i];
    _Float16 h = (_Float16)v;
    whi[i] = h;
    wlo[i] = (_Float16)((v - (float)h) * SCL);
  }
}

// R6 post-mortem: gl_lds staging serializes at ~190-200 cy PER INSTRUCTION per CU
// (R2: 32 instr -> 6210 cy/tile; R5/R6: 64 instr -> 12800; m97: 24 -> ~4440).
// The per-tile time was 100% staging DMA; MFMA needed only 1862 cy/SIMD (=11.9%
// MfmaUtil measured). Fix: reg-staged transport (global_load float4 -> rs[8] ->
// ds_write_b128, same addresses/swizzle) which pipelines at full VMEM rate, plus
// raw s_barrier with lgkmcnt(0)-only wait so prefetch loads for tile t+2 and att
// zero-stores stay IN FLIGHT across the per-tile barrier (counted-wait pattern;
// __syncthreads would emit vmcnt(0) and re-serialize).
__global__ __launch_bounds__(512, 2)
void fused_mem_kernel(const float* __restrict__ x, const float* __restrict__ wgt,
                      const _Float16* __restrict__ whi, const _Float16* __restrict__ wlo,
                      float* __restrict__ y_out, float* __restrict__ att_out) {
  // region: X stage f16[64][264] x2 = 67584 B -> B dbuf 2x65536 B -> yL f32[64][257]
  __shared__ __align__(16) float bufB[32768];       // 131072 B
  __shared__ int   lm[LCAP];
  __shared__ float le[LCAP];
  __shared__ float la[LCAP];
  __shared__ float Zred[256];
  __shared__ float invZ[TB];
  __shared__ float l1s[TB];
  __shared__ float dens[TB];
  __shared__ int   lcnt;
  _Float16* Xh = (_Float16*)bufB;
  _Float16* Xl = Xh + TB * XROW;
  float*    yL = bufB;
  char*     Bb = (char*)bufB;

  const int tid = threadIdx.x;
  const int wv  = tid >> 6;                 // 0..7
  const int l   = tid & 63;
  const int qw  = l >> 4;
  const int lr  = l & 15;
  const int mh  = wv & 3;                   // M quarter within 64-row tile
  const int tp  = wv >> 2;                  // token pair (32 tokens)
  const int t0  = blockIdx.x * TB;
  const int n   = t0 >> 10;
  const int hw0 = t0 & 1023;

  if (tid == 0) lcnt = 0;
  if (tid < TB) l1s[tid] = 0.f;

  // ---- phase 1: X tile (64 tokens x 256 c) -> LDS f16 hi/lo ----
  {
    const int h = tid & 63, cb = tid >> 6;
    const float* xp = x + ((size_t)n * Cc) * HW + hw0 + h;
    #pragma unroll
    for (int j = 0; j < 32; ++j) {
      int c = cb * 32 + j;
      float v = xp[(size_t)c * HW];          // 64 lanes consecutive: 256B chunks
      _Float16 hh = (_Float16)v;
      Xh[h * XROW + c] = hh;
      Xl[h * XROW + c] = (_Float16)((v - (float)hh) * SCL);
    }
  }
  __syncthreads();                                  // B1

  // A fragments: TWO 16-token sets per wave (tokens tp*32+0..15 and +16..31).
  // Per-set fragment contents/layout identical to the R2-verified mapping.
  f16x8 a0h[8], a0l[8], a1h[8], a1l[8];
  #pragma unroll
  for (int ks = 0; ks < 8; ++ks) {
    const int r0 = (tp * 32 + lr) * XROW + ks * 32 + qw * 8;
    const int r1 = (tp * 32 + 16 + lr) * XROW + ks * 32 + qw * 8;
    a0h[ks] = *(const f16x8*)&Xh[r0];
    a0l[ks] = *(const f16x8*)&Xl[r0];
    a1h[ks] = *(const f16x8*)&Xh[r1];
    a1l[ks] = *(const f16x8*)&Xl[r1];
  }
  __syncthreads();                                  // B1b: X region now free -> B dbuf

  // B staging, reg-staged (T14): global float4 loads -> rs[8] -> ds_write_b128.
  // Addresses/swizzle IDENTICAL to the gl_lds version (pre-swizzled source,
  // chunk ^= row&7; linear LDS dest in lane order).
  float4 rs[8];
  auto ldW = [&](int tile) {
    #pragma unroll
    for (int i = 0; i < 8; ++i) {
      const int u2 = i * 512 + wv * 64 + l;         // 0..4095
      const int r64 = (u2 >> 5) & 63;
      const int chunk = u2 & 31;
      int mrow = tile * 64 + r64; mrow = mrow < Mm ? mrow : (Mm - 1);  // tail clamp (rows unused)
      const char* src = (const char*)(i < 4 ? whi : wlo)
                      + (size_t)mrow * 512 + ((chunk ^ (r64 & 7)) << 4);
      rs[i] = *(const float4*)src;
    }
  };
  auto wrW = [&](int b) {
    char* base = Bb + b * 65536;
    #pragma unroll
    for (int i = 0; i < 8; ++i) {
      const int u2 = i * 512 + wv * 64 + l;
      *(float4*)(base + u2 * 16) = rs[i];           // compiler inserts graduated vmcnt waits
    }
  };

  // prologue: tile0 -> buf0; tile1 loads in flight across the barrier
  ldW(0);
  wrW(0);
  ldW(1);
  asm volatile("s_waitcnt lgkmcnt(0)" ::: "memory");
  __builtin_amdgcn_s_barrier();                     // buf0 published (no vmcnt drain)

  float zp0[4] = {0.f, 0.f, 0.f, 0.f};
  float zp1[4] = {0.f, 0.f, 0.f, 0.f};
  const int rrow = mh * 16 + lr;                    // W row within 64-row tile
  const int rsw  = rrow & 7;
  int cur = 0;
  for (int t = 0; t < NT; ++t) {
    // att background zeroing: fire-and-forget stores, never drained in-loop
    // (raw barrier waits lgkm only); fully drained at B2 before survivor writes.
    #pragma unroll
    for (int jj = 0; jj < 2; ++jj) {
      int m = t * 64 + jj * 32 + (tid >> 4);
      if (m < Mm) {
        f32x4 z4 = {0.f, 0.f, 0.f, 0.f};
        *(f32x4*)(att_out + ((size_t)(n * Mm + m)) * HW + hw0 + ((tid & 15) << 2)) = z4;
      }
    }

    if (t < NT - 1 || mh == 0) {                    // tail tile: 16 valid rows (mh==0 only)
      const char* bb = Bb + cur * 65536;
      f32x4 ahh0 = {0.f,0.f,0.f,0.f}, axl0 = {0.f,0.f,0.f,0.f}, alh0 = {0.f,0.f,0.f,0.f};
      f32x4 ahh1 = {0.f,0.f,0.f,0.f}, axl1 = {0.f,0.f,0.f,0.f}, alh1 = {0.f,0.f,0.f,0.f};
      #pragma unroll
      for (int kc = 0; kc < 2; ++kc) {              // B live range = 4 ks (32 regs)
        f16x8 bh[4], bl[4];
        #pragma unroll
        for (int k4 = 0; k4 < 4; ++k4) {
          const int ks = kc * 4 + k4;
          const int ch = rrow * 512 + (((ks * 4 + qw) ^ rsw) << 4);
          bh[k4] = *(const f16x8*)(bb + ch);
          bl[k4] = *(const f16x8*)(bb + 32768 + ch);
        }
        #pragma unroll
        for (int k4 = 0; k4 < 4; ++k4) {
          const int ks = kc * 4 + k4;
          ahh0 = __builtin_amdgcn_mfma_f32_16x16x32_f16(a0h[ks], bh[k4], ahh0, 0, 0, 0);
          axl0 = __builtin_amdgcn_mfma_f32_16x16x32_f16(a0h[ks], bl[k4], axl0, 0, 0, 0);
          alh0 = __builtin_amdgcn_mfma_f32_16x16x32_f16(a0l[ks], bh[k4], alh0, 0, 0, 0);
          ahh1 = __builtin_amdgcn_mfma_f32_16x16x32_f16(a1h[ks], bh[k4], ahh1, 0, 0, 0);
          axl1 = __builtin_amdgcn_mfma_f32_16x16x32_f16(a1h[ks], bl[k4], axl1, 0, 0, 0);
          alh1 = __builtin_amdgcn_mfma_f32_16x16x32_f16(a1l[ks], bh[k4], alh1, 0, 0, 0);
        }
      }
      const int mrow_ = t * 64 + rrow;
      #pragma unroll
      for (int r = 0; r < 4; ++r) {
        float s0 = fmaf(axl0[r] + alh0[r], ISCL, ahh0[r]);   // logit, bit-identical chains
        float e0 = __expf(s0);
        zp0[r] += e0;
        if (e0 > ECUT) {                                     // ~0.3% taken
          int slot = atomicAdd(&lcnt, 1);
          if (slot < LCAP) { lm[slot] = ((tp * 32 + qw * 4 + r) << 16) | mrow_; le[slot] = e0; }
        }
        float s1 = fmaf(axl1[r] + alh1[r], ISCL, ahh1[r]);
        float e1 = __expf(s1);
        zp1[r] += e1;
        if (e1 > ECUT) {
          int slot = atomicAdd(&lcnt, 1);
          if (slot < LCAP) { lm[slot] = ((tp * 32 + 16 + qw * 4 + r) << 16) | mrow_; le[slot] = e1; }
        }
      }
    }

    __builtin_amdgcn_sched_barrier(0);              // keep staging writes AFTER compute
    if (t + 1 < NT) wrW(cur ^ 1);                   // tile t+1 regs -> LDS (vmcnt waits ~0 now)
    if (t + 2 < NT) ldW(t + 2);                     // prefetch flies across the barrier
    asm volatile("s_waitcnt lgkmcnt(0)" ::: "memory");   // ds_writes visible
    __builtin_amdgcn_s_barrier();                   // NO vmcnt drain: loads/stores stay in flight
    cur ^= 1;
  }

  #pragma unroll
  for (int o = 1; o < 16; o <<= 1)
    #pragma unroll
    for (int r = 0; r < 4; ++r) {
      zp0[r] += __shfl_xor(zp0[r], o);
      zp1[r] += __shfl_xor(zp1[r], o);
    }
  if (lr == 0) {
    #pragma unroll
    for (int r = 0; r < 4; ++r) {
      Zred[mh * 64 + tp * 32 + qw * 4 + r]      = zp0[r];
      Zred[mh * 64 + tp * 32 + 16 + qw * 4 + r] = zp1[r];
    }
  }
  __syncthreads();                                  // B2 (full drain: att zero-stores land here)

  if (tid < TB)
    invZ[tid] = 1.f / (Zred[tid] + Zred[64 + tid] + Zred[128 + tid] + Zred[192 + tid]);
  __syncthreads();                                  // B3

  // ---- phase 4: candidate scan (exact fp32 recompute of borderline) + L1 ----
  const int ne = min(lcnt, LCAP);
  for (int e = tid; e < ne; e += 512) {
    const int tm = lm[e];
    const int t = tm >> 16, m = tm & 0xFFFF;
    float p = le[e] * invZ[t];
    float a = 0.f;
    if (p > PLO) {
      float pu = p;
      if (p < PHI) {
        // borderline (~few per block): exact fp32 dot from global x, W
        const float* xr = x + ((size_t)n * Cc) * HW + hw0 + t;
        const float* wr = wgt + (size_t)m * Cc;
        float s = 0.f;
        for (int c = 0; c < Cc; ++c) s = fmaf(xr[(size_t)c * HW], wr[c], s);
        pu = expf(s) * invZ[t];
      }
      float d = pu - LAMBDA;
      if (d > 0.f) {
        a = (d * pu) / (d + 1e-12f);
        atomicAdd(&l1s[t], a);
      }
    }
    la[e] = a;
  }
  __syncthreads();                                  // B4

  if (tid < TB) dens[tid] = fmaxf(l1s[tid], 1e-12f);
  for (int i = tid; i < TB * YROW; i += 512) yL[i] = 0.f;   // B dbuf dead; alias reuse
  __syncthreads();                                  // B5

  // ---- phase 6: sparse GEMM2 from survivor list (fp32 W) + att scatter ----
  // y accum layout PERMUTED: channel c lives at t*YROW + ((c&3)<<6 | c>>2) so the
  // atomics have 4B lane stride (2 lanes/bank = free).
  for (int e = wv; e < ne; e += 8) {                // wave-uniform entry -> no divergence
    float av = la[e];
    if (av > 0.f) {
      const int tm = lm[e];
      const int t = tm >> 16, m = tm & 0xFFFF;
      const float a = av / dens[t];
      float4 wf = *(const float4*)(wgt + (size_t)m * Cc + l * 4);   // c = 4l+i
      float* yr = yL + t * YROW + l;                // acc idx of c=4l+i is (i<<6)+l
      atomicAdd(yr + 0,   a * wf.x);
      atomicAdd(yr + 64,  a * wf.y);
      atomicAdd(yr + 128, a * wf.z);
      atomicAdd(yr + 192, a * wf.w);
      if (l == 0)
        att_out[((size_t)(n * Mm + m)) * HW + hw0 + t] = a;   // bg zeroed in-loop above
    }
  }
  __syncthreads();                                  // B6

  // ---- phase 7: y write (256B chunks: 64 consecutive hw per c); un-permute accum ----
  {
    const int h = tid & 63, cb = tid >> 6;
    float* yp = y_out + ((size_t)n * Cc) * HW + hw0 + h;
    #pragma unroll
    for (int j = 0; j < 32; ++j) {
      int c = cb * 32 + j;
      yp[(size_t)c * HW] = yL[h * YROW + (((c & 3) << 6) | (c >> 2))];
    }
  }
}

extern "C" void kernel_launch(void* const* d_in, const int* in_sizes, int n_in,
                              void* d_out, int out_size, void* d_ws, size_t ws_size,
                              hipStream_t stream) {
  const float* x = (const float*)d_in[0];
  const float* w = (const float*)d_in[1];
  float* y_out   = (float*)d_out;
  float* att_out = y_out + (size_t)Nn * Cc * HW;
  _Float16* whi = (_Float16*)d_ws;                  // 1.024 MB
  _Float16* wlo = whi + (size_t)Mm * Cc;            // 1.024 MB

  // att background zeroed in-kernel (block-exclusive slices, fire-and-forget under
  // the raw barriers). R5-vs-R6 totals showed in-kernel wins over memset by ~28us.
  wcvt_kernel<<<(Mm * Cc + 255) / 256, 256, 0, stream>>>(w, whi, wlo);
  fused_mem_kernel<<<Tt / TB, 512, 0, stream>>>(x, w, whi, wlo, y_out, att_out);
}

// Round 8
// 795.600 us; speedup vs baseline: 1.0228x; 1.0228x over previous
//
#include <hip/hip_runtime.h>

typedef _Float16 f16x8 __attribute__((ext_vector_type(8)));
typedef float    f32x4 __attribute__((ext_vector_type(4)));

constexpr int Nn = 32, Cc = 256, HW = 1024, Mm = 2000, Tt = 32768;
constexpr int TB = 64;        // tokens per block (2 token-pairs x 32)
constexpr int XROW = 264;     // X row stride (f16): 528 B rows, 16B-aligned rows
constexpr int YROW = 257;     // y accum row stride (fp32)
constexpr int LCAP = 768;     // candidate cap (expected ~436/block; validated R4-R7)
constexpr int NT = 32;        // M tiles of 64 rows (31 full + 16-row tail)
constexpr float LAMBDA = 0.0025f;
constexpr float PLO = LAMBDA * (1.0f - 3e-3f);   // borderline window (covers GEMM noise + Z regroup)
constexpr float PHI = LAMBDA * (1.0f + 3e-3f);
constexpr float ECUT = 4.8f;  // candidate cut (per-logit e bits unchanged -> same set)
constexpr float SCL = 4096.0f, ISCL = 1.0f / 4096.0f;

__global__ void wcvt_kernel(const float* __restrict__ w,
                            _Float16* __restrict__ whi, _Float16* __restrict__ wlo) {
  int i = blockIdx.x * 256 + threadIdx.x;
  if (i < Mm * Cc) {
    float v = w[i];
    _Float16 h = (_Float16)v;
    whi[i] = h;
    wlo[i] = (_Float16)((v - (float)h) * SCL);
  }
}

// R7 post-mortem: the reg-staging design was right but rs[8] was lambda-captured
// by reference -> addressable -> the "memory"-clobber waitcnt asm forced it to a
// stack home -> 128 B/thread/iter scratch (exactly the +1.04 GB WRITE_SIZE).
// R8: identical transport, spill-proof codegen -- staging inlined via macros, rs
// indexed only by compile-time constants (SSA after unroll; "memory" clobbers
// can't touch register-only values). Barrier discipline unchanged: raw s_barrier
// + lgkmcnt(0)-only wait; global loads for tile t+2 and att zero-stores stay in
// flight across barriers; __syncthreads (vmcnt(0) drain) only after the loop.
__global__ __launch_bounds__(512, 2)
void fused_mem_kernel(const float* __restrict__ x, const float* __restrict__ wgt,
                      const _Float16* __restrict__ whi, const _Float16* __restrict__ wlo,
                      float* __restrict__ y_out, float* __restrict__ att_out) {
  // region: X stage f16[64][264] x2 = 67584 B -> B dbuf 2x65536 B -> yL f32[64][257]
  __shared__ __align__(16) float bufB[32768];       // 131072 B
  __shared__ int   lm[LCAP];
  __shared__ float le[LCAP];
  __shared__ float la[LCAP];
  __shared__ float Zred[256];
  __shared__ float invZ[TB];
  __shared__ float l1s[TB];
  __shared__ float dens[TB];
  __shared__ int   lcnt;
  _Float16* Xh = (_Float16*)bufB;
  _Float16* Xl = Xh + TB * XROW;
  float*    yL = bufB;
  char*     Bb = (char*)bufB;

  const int tid = threadIdx.x;
  const int wv  = tid >> 6;                 // 0..7
  const int l   = tid & 63;
  const int qw  = l >> 4;
  const int lr  = l & 15;
  const int mh  = wv & 3;                   // M quarter within 64-row tile
  const int tp  = wv >> 2;                  // token pair (32 tokens)
  const int t0  = blockIdx.x * TB;
  const int n   = t0 >> 10;
  const int hw0 = t0 & 1023;

  if (tid == 0) lcnt = 0;
  if (tid < TB) l1s[tid] = 0.f;

  // ---- phase 1: X tile (64 tokens x 256 c) -> LDS f16 hi/lo ----
  {
    const int h = tid & 63, cb = tid >> 6;
    const float* xp = x + ((size_t)n * Cc) * HW + hw0 + h;
    #pragma unroll
    for (int j = 0; j < 32; ++j) {
      int c = cb * 32 + j;
      float v = xp[(size_t)c * HW];          // 64 lanes consecutive: 256B chunks
      _Float16 hh = (_Float16)v;
      Xh[h * XROW + c] = hh;
      Xl[h * XROW + c] = (_Float16)((v - (float)hh) * SCL);
    }
  }
  __syncthreads();                                  // B1

  // A fragments: TWO 16-token sets per wave (tokens tp*32+0..15 and +16..31).
  // Per-set fragment contents/layout identical to the R2-verified mapping.
  f16x8 a0h[8], a0l[8], a1h[8], a1l[8];
  #pragma unroll
  for (int ks = 0; ks < 8; ++ks) {
    const int r0 = (tp * 32 + lr) * XROW + ks * 32 + qw * 8;
    const int r1 = (tp * 32 + 16 + lr) * XROW + ks * 32 + qw * 8;
    a0h[ks] = *(const f16x8*)&Xh[r0];
    a0l[ks] = *(const f16x8*)&Xl[r0];
    a1h[ks] = *(const f16x8*)&Xh[r1];
    a1l[ks] = *(const f16x8*)&Xl[r1];
  }
  __syncthreads();                                  // B1b: X region now free -> B dbuf

  // B staging, reg-staged: global float4 loads -> rs[8] -> ds_write_b128.
  // Addresses/swizzle IDENTICAL to R5-R7 (pre-swizzled source chunk ^= row&7;
  // linear LDS dest in lane order). NO lambdas: rs must stay SSA (R7 lesson).
  float4 rs[8];
#define LDW(TILE) do {                                                        \
    _Pragma("unroll")                                                         \
    for (int i_ = 0; i_ < 8; ++i_) {                                          \
      const int u2_ = i_ * 512 + wv * 64 + l;                                 \
      const int r64_ = (u2_ >> 5) & 63;                                       \
      const int ck_ = u2_ & 31;                                               \
      int mr_ = (TILE) * 64 + r64_; mr_ = mr_ < Mm ? mr_ : (Mm - 1);          \
      const char* s_ = (const char*)(i_ < 4 ? whi : wlo)                      \
                     + (size_t)mr_ * 512 + ((ck_ ^ (r64_ & 7)) << 4);         \
      rs[i_] = *(const float4*)s_;                                            \
    }                                                                         \
  } while (0)
#define WRW(B) do {                                                           \
    char* b_ = Bb + (B) * 65536;                                              \
    _Pragma("unroll")                                                         \
    for (int i_ = 0; i_ < 8; ++i_) {                                          \
      const int u2_ = i_ * 512 + wv * 64 + l;                                 \
      *(float4*)(b_ + u2_ * 16) = rs[i_];                                     \
    }                                                                         \
  } while (0)

  // prologue: tile0 -> buf0; tile1 loads in flight across the barrier
  LDW(0);
  WRW(0);
  LDW(1);
  asm volatile("s_waitcnt lgkmcnt(0)" ::: "memory");
  __builtin_amdgcn_s_barrier();                     // buf0 published (no vmcnt drain)

  float zp0[4] = {0.f, 0.f, 0.f, 0.f};
  float zp1[4] = {0.f, 0.f, 0.f, 0.f};
  const int rrow = mh * 16 + lr;                    // W row within 64-row tile
  const int rsw  = rrow & 7;
  int cur = 0;
  for (int t = 0; t < NT; ++t) {
    // att background zeroing: fire-and-forget stores, never drained in-loop
    // (raw barrier waits lgkm only); fully drained at B2 before survivor writes.
    #pragma unroll
    for (int jj = 0; jj < 2; ++jj) {
      int m = t * 64 + jj * 32 + (tid >> 4);
      if (m < Mm) {
        f32x4 z4 = {0.f, 0.f, 0.f, 0.f};
        *(f32x4*)(att_out + ((size_t)(n * Mm + m)) * HW + hw0 + ((tid & 15) << 2)) = z4;
      }
    }

    if (t < NT - 1 || mh == 0) {                    // tail tile: 16 valid rows (mh==0 only)
      const char* bb = Bb + cur * 65536;
      f32x4 ahh0 = {0.f,0.f,0.f,0.f}, axl0 = {0.f,0.f,0.f,0.f}, alh0 = {0.f,0.f,0.f,0.f};
      f32x4 ahh1 = {0.f,0.f,0.f,0.f}, axl1 = {0.f,0.f,0.f,0.f}, alh1 = {0.f,0.f,0.f,0.f};
      #pragma unroll
      for (int kc = 0; kc < 2; ++kc) {              // B live range = 4 ks (32 regs)
        f16x8 bh[4], bl[4];
        #pragma unroll
        for (int k4 = 0; k4 < 4; ++k4) {
          const int ks = kc * 4 + k4;
          const int ch = rrow * 512 + (((ks * 4 + qw) ^ rsw) << 4);
          bh[k4] = *(const f16x8*)(bb + ch);
          bl[k4] = *(const f16x8*)(bb + 32768 + ch);
        }
        #pragma unroll
        for (int k4 = 0; k4 < 4; ++k4) {
          const int ks = kc * 4 + k4;
          ahh0 = __builtin_amdgcn_mfma_f32_16x16x32_f16(a0h[ks], bh[k4], ahh0, 0, 0, 0);
          axl0 = __builtin_amdgcn_mfma_f32_16x16x32_f16(a0h[ks], bl[k4], axl0, 0, 0, 0);
          alh0 = __builtin_amdgcn_mfma_f32_16x16x32_f16(a0l[ks], bh[k4], alh0, 0, 0, 0);
          ahh1 = __builtin_amdgcn_mfma_f32_16x16x32_f16(a1h[ks], bh[k4], ahh1, 0, 0, 0);
          axl1 = __builtin_amdgcn_mfma_f32_16x16x32_f16(a1h[ks], bl[k4], axl1, 0, 0, 0);
          alh1 = __builtin_amdgcn_mfma_f32_16x16x32_f16(a1l[ks], bh[k4], alh1, 0, 0, 0);
        }
      }
      const int mrow_ = t * 64 + rrow;
      #pragma unroll
      for (int r = 0; r < 4; ++r) {
        float s0 = fmaf(axl0[r] + alh0[r], ISCL, ahh0[r]);   // logit, bit-identical chains
        float e0 = __expf(s0);
        zp0[r] += e0;
        if (e0 > ECUT) {                                     // ~0.3% taken
          int slot = atomicAdd(&lcnt, 1);
          if (slot < LCAP) { lm[slot] = ((tp * 32 + qw * 4 + r) << 16) | mrow_; le[slot] = e0; }
        }
        float s1 = fmaf(axl1[r] + alh1[r], ISCL, ahh1[r]);
        float e1 = __expf(s1);
        zp1[r] += e1;
        if (e1 > ECUT) {
          int slot = atomicAdd(&lcnt, 1);
          if (slot < LCAP) { lm[slot] = ((tp * 32 + 16 + qw * 4 + r) << 16) | mrow_; le[slot] = e1; }
        }
      }
    }

    __builtin_amdgcn_sched_barrier(0);              // keep staging writes AFTER compute
    if (t + 1 < NT) WRW(cur ^ 1);                   // tile t+1 regs -> LDS (graduated vmcnt, ~0 wait)
    if (t + 2 < NT) LDW(t + 2);                     // prefetch flies across the barrier
    asm volatile("s_waitcnt lgkmcnt(0)" ::: "memory");   // ds_writes visible to all waves
    __builtin_amdgcn_s_barrier();                   // NO vmcnt drain: loads/stores stay in flight
    cur ^= 1;
  }
#undef LDW
#undef WRW

  #pragma unroll
  for (int o = 1; o < 16; o <<= 1)
    #pragma unroll
    for (int r = 0; r < 4; ++r) {
      zp0[r] += __shfl_xor(zp0[r], o);
      zp1[r] += __shfl_xor(zp1[r], o);
    }
  if (lr == 0) {
    #pragma unroll
    for (int r = 0; r < 4; ++r) {
      Zred[mh * 64 + tp * 32 + qw * 4 + r]      = zp0[r];
      Zred[mh * 64 + tp * 32 + 16 + qw * 4 + r] = zp1[r];
    }
  }
  __syncthreads();                                  // B2 (full drain: att zero-stores land here)

  if (tid < TB)
    invZ[tid] = 1.f / (Zred[tid] + Zred[64 + tid] + Zred[128 + tid] + Zred[192 + tid]);
  __syncthreads();                                  // B3

  // ---- phase 4: candidate scan (exact fp32 recompute of borderline) + L1 ----
  const int ne = min(lcnt, LCAP);
  for (int e = tid; e < ne; e += 512) {
    const int tm = lm[e];
    const int t = tm >> 16, m = tm & 0xFFFF;
    float p = le[e] * invZ[t];
    float a = 0.f;
    if (p > PLO) {
      float pu = p;
      if (p < PHI) {
        // borderline (~few per block): exact fp32 dot from global x, W
        const float* xr = x + ((size_t)n * Cc) * HW + hw0 + t;
        const float* wr = wgt + (size_t)m * Cc;
        float s = 0.f;
        for (int c = 0; c < Cc; ++c) s = fmaf(xr[(size_t)c * HW], wr[c], s);
        pu = expf(s) * invZ[t];
      }
      float d = pu - LAMBDA;
      if (d > 0.f) {
        a = (d * pu) / (d + 1e-12f);
        atomicAdd(&l1s[t], a);
      }
    }
    la[e] = a;
  }
  __syncthreads();                                  // B4

  if (tid < TB) dens[tid] = fmaxf(l1s[tid], 1e-12f);
  for (int i = tid; i < TB * YROW; i += 512) yL[i] = 0.f;   // B dbuf dead; alias reuse
  __syncthreads();                                  // B5

  // ---- phase 6: sparse GEMM2 from survivor list (fp32 W) + att scatter ----
  // y accum layout PERMUTED: channel c lives at t*YROW + ((c&3)<<6 | c>>2) so the
  // atomics have 4B lane stride (2 lanes/bank = free).
  for (int e = wv; e < ne; e += 8) {                // wave-uniform entry -> no divergence
    float av = la[e];
    if (av > 0.f) {
      const int tm = lm[e];
      const int t = tm >> 16, m = tm & 0xFFFF;
      const float a = av / dens[t];
      float4 wf = *(const float4*)(wgt + (size_t)m * Cc + l * 4);   // c = 4l+i
      float* yr = yL + t * YROW + l;                // acc idx of c=4l+i is (i<<6)+l
      atomicAdd(yr + 0,   a * wf.x);
      atomicAdd(yr + 64,  a * wf.y);
      atomicAdd(yr + 128, a * wf.z);
      atomicAdd(yr + 192, a * wf.w);
      if (l == 0)
        att_out[((size_t)(n * Mm + m)) * HW + hw0 + t] = a;   // bg zeroed in-loop above
    }
  }
  __syncthreads();                                  // B6

  // ---- phase 7: y write (256B chunks: 64 consecutive hw per c); un-permute accum ----
  {
    const int h = tid & 63, cb = tid >> 6;
    float* yp = y_out + ((size_t)n * Cc) * HW + hw0 + h;
    #pragma unroll
    for (int j = 0; j < 32; ++j) {
      int c = cb * 32 + j;
      yp[(size_t)c * HW] = yL[h * YROW + (((c & 3) << 6) | (c >> 2))];
    }
  }
}

extern "C" void kernel_launch(void* const* d_in, const int* in_sizes, int n_in,
                              void* d_out, int out_size, void* d_ws, size_t ws_size,
                              hipStream_t stream) {
  const float* x = (const float*)d_in[0];
  const float* w = (const float*)d_in[1];
  float* y_out   = (float*)d_out;
  float* att_out = y_out + (size_t)Nn * Cc * HW;
  _Float16* whi = (_Float16*)d_ws;                  // 1.024 MB
  _Float16* wlo = whi + (size_t)Mm * Cc;            // 1.024 MB

  // att background zeroed in-kernel (block-exclusive slices, fire-and-forget under
  // the raw barriers). R5-vs-R6 totals showed in-kernel wins over memset by ~28us.
  wcvt_kernel<<<(Mm * Cc + 255) / 256, 256, 0, stream>>>(w, whi, wlo);
  fused_mem_kernel<<<Tt / TB, 512, 0, stream>>>(x, w, whi, wlo, y_out, att_out);
}

// Round 9
// 615.148 us; speedup vs baseline: 1.3228x; 1.2933x over previous
//
#include <hip/hip_runtime.h>

typedef _Float16 f16x8 __attribute__((ext_vector_type(8)));
typedef float    f32x4 __attribute__((ext_vector_type(4)));

constexpr int Nn = 32, Cc = 256, HW = 1024, Mm = 2000, Tt = 32768;
constexpr int TB = 64;        // tokens per block (2 token-pairs x 32)
constexpr int XROW = 264;     // X row stride (f16): 528 B rows, 16B-aligned rows
constexpr int YROW = 257;     // y accum row stride (fp32)
constexpr int LCAP = 768;     // candidate cap (expected ~436/block; validated R4-R8)
constexpr int NT = 32;        // M tiles of 64 rows (31 full + 16-row tail)
constexpr float LAMBDA = 0.0025f;
constexpr float PLO = LAMBDA * (1.0f - 3e-3f);   // borderline window (covers GEMM noise + Z regroup)
constexpr float PHI = LAMBDA * (1.0f + 3e-3f);
constexpr float ECUT = 4.8f;  // candidate cut (per-logit e bits unchanged -> same set)
constexpr float SCL = 4096.0f, ISCL = 1.0f / 4096.0f;

__global__ void wcvt_kernel(const float* __restrict__ w,
                            _Float16* __restrict__ whi, _Float16* __restrict__ wlo) {
  int i = blockIdx.x * 256 + threadIdx.x;
  if (i < Mm * Cc) {
    float v = w[i];
    _Float16 h = (_Float16)v;
    whi[i] = h;
    wlo[i] = (_Float16)((v - (float)h) * SCL);
  }
}

// R8 post-mortem: the spill wasn't codegen -- it was PRESSURE. With LDW(t+2) deep
// prefetch, rs[8] (32 VGPR) was live across the whole compute phase; peak set
// (A-frags 128 + bh/bl 32 + acc 24 + zp 8 + rs 32 + addr) > the 256-reg (512,2)
// budget -> allocator spilled rs = exactly the 770MB scratch WRITE observed.
// R9: LDW(t+1) moved ADJACENT to WRW at loop bottom -- rs live range ~8 instrs,
// nothing staged across compute. Cost: ~250-400cy exposed L2 latency per tile
// (vs ~2.5k cy tile budget); gain: zero scratch. Raw s_barrier + lgkmcnt-only
// waits kept (no gl_lds 190cy/instr serializer, no vmcnt(0) drains in-loop).
__global__ __launch_bounds__(512, 2)
void fused_mem_kernel(const float* __restrict__ x, const float* __restrict__ wgt,
                      const _Float16* __restrict__ whi, const _Float16* __restrict__ wlo,
                      float* __restrict__ y_out, float* __restrict__ att_out) {
  // region: X stage f16[64][264] x2 = 67584 B -> B dbuf 2x65536 B -> yL f32[64][257]
  __shared__ __align__(16) float bufB[32768];       // 131072 B
  __shared__ int   lm[LCAP];
  __shared__ float le[LCAP];
  __shared__ float la[LCAP];
  __shared__ float Zred[256];
  __shared__ float invZ[TB];
  __shared__ float l1s[TB];
  __shared__ float dens[TB];
  __shared__ int   lcnt;
  _Float16* Xh = (_Float16*)bufB;
  _Float16* Xl = Xh + TB * XROW;
  float*    yL = bufB;
  char*     Bb = (char*)bufB;

  const int tid = threadIdx.x;
  const int wv  = tid >> 6;                 // 0..7
  const int l   = tid & 63;
  const int qw  = l >> 4;
  const int lr  = l & 15;
  const int mh  = wv & 3;                   // M quarter within 64-row tile
  const int tp  = wv >> 2;                  // token pair (32 tokens)
  const int t0  = blockIdx.x * TB;
  const int n   = t0 >> 10;
  const int hw0 = t0 & 1023;

  if (tid == 0) lcnt = 0;
  if (tid < TB) l1s[tid] = 0.f;

  // ---- phase 1: X tile (64 tokens x 256 c) -> LDS f16 hi/lo ----
  {
    const int h = tid & 63, cb = tid >> 6;
    const float* xp = x + ((size_t)n * Cc) * HW + hw0 + h;
    #pragma unroll
    for (int j = 0; j < 32; ++j) {
      int c = cb * 32 + j;
      float v = xp[(size_t)c * HW];          // 64 lanes consecutive: 256B chunks
      _Float16 hh = (_Float16)v;
      Xh[h * XROW + c] = hh;
      Xl[h * XROW + c] = (_Float16)((v - (float)hh) * SCL);
    }
  }
  __syncthreads();                                  // B1

  // A fragments: TWO 16-token sets per wave (tokens tp*32+0..15 and +16..31).
  // Per-set fragment contents/layout identical to the R2-verified mapping.
  f16x8 a0h[8], a0l[8], a1h[8], a1l[8];
  #pragma unroll
  for (int ks = 0; ks < 8; ++ks) {
    const int r0 = (tp * 32 + lr) * XROW + ks * 32 + qw * 8;
    const int r1 = (tp * 32 + 16 + lr) * XROW + ks * 32 + qw * 8;
    a0h[ks] = *(const f16x8*)&Xh[r0];
    a0l[ks] = *(const f16x8*)&Xl[r0];
    a1h[ks] = *(const f16x8*)&Xh[r1];
    a1l[ks] = *(const f16x8*)&Xl[r1];
  }
  __syncthreads();                                  // B1b: X region now free -> B dbuf

  // B staging, reg-staged: global float4 loads -> rs[8] -> ds_write_b128.
  // Addresses/swizzle IDENTICAL to R5-R8 (pre-swizzled source chunk ^= row&7;
  // linear LDS dest in lane order). LDW/WRW are ADJACENT so rs never lives
  // across compute (R8 lesson: that liveness == guaranteed spill).
  float4 rs[8];
#define LDW(TILE) do {                                                        \
    _Pragma("unroll")                                                         \
    for (int i_ = 0; i_ < 8; ++i_) {                                          \
      const int u2_ = i_ * 512 + wv * 64 + l;                                 \
      const int r64_ = (u2_ >> 5) & 63;                                       \
      const int ck_ = u2_ & 31;                                               \
      int mr_ = (TILE) * 64 + r64_; mr_ = mr_ < Mm ? mr_ : (Mm - 1);          \
      const char* s_ = (const char*)(i_ < 4 ? whi : wlo)                      \
                     + (size_t)mr_ * 512 + ((ck_ ^ (r64_ & 7)) << 4);         \
      rs[i_] = *(const float4*)s_;                                            \
    }                                                                         \
  } while (0)
#define WRW(B) do {                                                           \
    char* b_ = Bb + (B) * 65536;                                              \
    _Pragma("unroll")                                                         \
    for (int i_ = 0; i_ < 8; ++i_) {                                          \
      const int u2_ = i_ * 512 + wv * 64 + l;                                 \
      *(float4*)(b_ + u2_ * 16) = rs[i_];                                     \
    }                                                                         \
  } while (0)

  // prologue: tile0 -> buf0
  LDW(0);
  WRW(0);
  asm volatile("s_waitcnt lgkmcnt(0)" ::: "memory");
  __builtin_amdgcn_s_barrier();                     // buf0 published (no vmcnt drain)

  float zp0[4] = {0.f, 0.f, 0.f, 0.f};
  float zp1[4] = {0.f, 0.f, 0.f, 0.f};
  const int rrow = mh * 16 + lr;                    // W row within 64-row tile
  const int rsw  = rrow & 7;
  int cur = 0;
  for (int t = 0; t < NT; ++t) {
    // att background zeroing: fire-and-forget stores, never drained in-loop
    // (raw barrier waits lgkm only); fully drained at B2 before survivor writes.
    #pragma unroll
    for (int jj = 0; jj < 2; ++jj) {
      int m = t * 64 + jj * 32 + (tid >> 4);
      if (m < Mm) {
        f32x4 z4 = {0.f, 0.f, 0.f, 0.f};
        *(f32x4*)(att_out + ((size_t)(n * Mm + m)) * HW + hw0 + ((tid & 15) << 2)) = z4;
      }
    }

    if (t < NT - 1 || mh == 0) {                    // tail tile: 16 valid rows (mh==0 only)
      const char* bb = Bb + cur * 65536;
      f32x4 ahh0 = {0.f,0.f,0.f,0.f}, axl0 = {0.f,0.f,0.f,0.f}, alh0 = {0.f,0.f,0.f,0.f};
      f32x4 ahh1 = {0.f,0.f,0.f,0.f}, axl1 = {0.f,0.f,0.f,0.f}, alh1 = {0.f,0.f,0.f,0.f};
      #pragma unroll
      for (int kc = 0; kc < 2; ++kc) {              // B live range = 4 ks (32 regs)
        f16x8 bh[4], bl[4];
        #pragma unroll
        for (int k4 = 0; k4 < 4; ++k4) {
          const int ks = kc * 4 + k4;
          const int ch = rrow * 512 + (((ks * 4 + qw) ^ rsw) << 4);
          bh[k4] = *(const f16x8*)(bb + ch);
          bl[k4] = *(const f16x8*)(bb + 32768 + ch);
        }
        #pragma unroll
        for (int k4 = 0; k4 < 4; ++k4) {
          const int ks = kc * 4 + k4;
          ahh0 = __builtin_amdgcn_mfma_f32_16x16x32_f16(a0h[ks], bh[k4], ahh0, 0, 0, 0);
          axl0 = __builtin_amdgcn_mfma_f32_16x16x32_f16(a0h[ks], bl[k4], axl0, 0, 0, 0);
          alh0 = __builtin_amdgcn_mfma_f32_16x16x32_f16(a0l[ks], bh[k4], alh0, 0, 0, 0);
          ahh1 = __builtin_amdgcn_mfma_f32_16x16x32_f16(a1h[ks], bh[k4], ahh1, 0, 0, 0);
          axl1 = __builtin_amdgcn_mfma_f32_16x16x32_f16(a1h[ks], bl[k4], axl1, 0, 0, 0);
          alh1 = __builtin_amdgcn_mfma_f32_16x16x32_f16(a1l[ks], bh[k4], alh1, 0, 0, 0);
        }
      }
      const int mrow_ = t * 64 + rrow;
      #pragma unroll
      for (int r = 0; r < 4; ++r) {
        float s0 = fmaf(axl0[r] + alh0[r], ISCL, ahh0[r]);   // logit, bit-identical chains
        float e0 = __expf(s0);
        zp0[r] += e0;
        if (e0 > ECUT) {                                     // ~0.3% taken
          int slot = atomicAdd(&lcnt, 1);
          if (slot < LCAP) { lm[slot] = ((tp * 32 + qw * 4 + r) << 16) | mrow_; le[slot] = e0; }
        }
        float s1 = fmaf(axl1[r] + alh1[r], ISCL, ahh1[r]);
        float e1 = __expf(s1);
        zp1[r] += e1;
        if (e1 > ECUT) {
          int slot = atomicAdd(&lcnt, 1);
          if (slot < LCAP) { lm[slot] = ((tp * 32 + 16 + qw * 4 + r) << 16) | mrow_; le[slot] = e1; }
        }
      }
    }

    __builtin_amdgcn_sched_barrier(0);              // staging stays BELOW compute (no hoist)
    if (t + 1 < NT) {
      LDW(t + 1);                                   // adjacent load+write: rs live ~8 instrs
      WRW(cur ^ 1);                                 // graduated vmcnt waits (~400cy, L2-resident W)
    }
    asm volatile("s_waitcnt lgkmcnt(0)" ::: "memory");   // ds_writes visible to all waves
    __builtin_amdgcn_s_barrier();                   // NO vmcnt drain: att stores stay in flight
    cur ^= 1;
  }
#undef LDW
#undef WRW

  #pragma unroll
  for (int o = 1; o < 16; o <<= 1)
    #pragma unroll
    for (int r = 0; r < 4; ++r) {
      zp0[r] += __shfl_xor(zp0[r], o);
      zp1[r] += __shfl_xor(zp1[r], o);
    }
  if (lr == 0) {
    #pragma unroll
    for (int r = 0; r < 4; ++r) {
      Zred[mh * 64 + tp * 32 + qw * 4 + r]      = zp0[r];
      Zred[mh * 64 + tp * 32 + 16 + qw * 4 + r] = zp1[r];
    }
  }
  __syncthreads();                                  // B2 (full drain: att zero-stores land here)

  if (tid < TB)
    invZ[tid] = 1.f / (Zred[tid] + Zred[64 + tid] + Zred[128 + tid] + Zred[192 + tid]);
  __syncthreads();                                  // B3

  // ---- phase 4: candidate scan (exact fp32 recompute of borderline) + L1 ----
  const int ne = min(lcnt, LCAP);
  for (int e = tid; e < ne; e += 512) {
    const int tm = lm[e];
    const int t = tm >> 16, m = tm & 0xFFFF;
    float p = le[e] * invZ[t];
    float a = 0.f;
    if (p > PLO) {
      float pu = p;
      if (p < PHI) {
        // borderline (~few per block): exact fp32 dot from global x, W
        const float* xr = x + ((size_t)n * Cc) * HW + hw0 + t;
        const float* wr = wgt + (size_t)m * Cc;
        float s = 0.f;
        for (int c = 0; c < Cc; ++c) s = fmaf(xr[(size_t)c * HW], wr[c], s);
        pu = expf(s) * invZ[t];
      }
      float d = pu - LAMBDA;
      if (d > 0.f) {
        a = (d * pu) / (d + 1e-12f);
        atomicAdd(&l1s[t], a);
      }
    }
    la[e] = a;
  }
  __syncthreads();                                  // B4

  if (tid < TB) dens[tid] = fmaxf(l1s[tid], 1e-12f);
  for (int i = tid; i < TB * YROW; i += 512) yL[i] = 0.f;   // B dbuf dead; alias reuse
  __syncthreads();                                  // B5

  // ---- phase 6: sparse GEMM2 from survivor list (fp32 W) + att scatter ----
  // y accum layout PERMUTED: channel c lives at t*YROW + ((c&3)<<6 | c>>2) so the
  // atomics have 4B lane stride (2 lanes/bank = free).
  for (int e = wv; e < ne; e += 8) {                // wave-uniform entry -> no divergence
    float av = la[e];
    if (av > 0.f) {
      const int tm = lm[e];
      const int t = tm >> 16, m = tm & 0xFFFF;
      const float a = av / dens[t];
      float4 wf = *(const float4*)(wgt + (size_t)m * Cc + l * 4);   // c = 4l+i
      float* yr = yL + t * YROW + l;                // acc idx of c=4l+i is (i<<6)+l
      atomicAdd(yr + 0,   a * wf.x);
      atomicAdd(yr + 64,  a * wf.y);
      atomicAdd(yr + 128, a * wf.z);
      atomicAdd(yr + 192, a * wf.w);
      if (l == 0)
        att_out[((size_t)(n * Mm + m)) * HW + hw0 + t] = a;   // bg zeroed in-loop above
    }
  }
  __syncthreads();                                  // B6

  // ---- phase 7: y write (256B chunks: 64 consecutive hw per c); un-permute accum ----
  {
    const int h = tid & 63, cb = tid >> 6;
    float* yp = y_out + ((size_t)n * Cc) * HW + hw0 + h;
    #pragma unroll
    for (int j = 0; j < 32; ++j) {
      int c = cb * 32 + j;
      yp[(size_t)c * HW] = yL[h * YROW + (((c & 3) << 6) | (c >> 2))];
    }
  }
}

extern "C" void kernel_launch(void* const* d_in, const int* in_sizes, int n_in,
                              void* d_out, int out_size, void* d_ws, size_t ws_size,
                              hipStream_t stream) {
  const float* x = (const float*)d_in[0];
  const float* w = (const float*)d_in[1];
  float* y_out   = (float*)d_out;
  float* att_out = y_out + (size_t)Nn * Cc * HW;
  _Float16* whi = (_Float16*)d_ws;                  // 1.024 MB
  _Float16* wlo = whi + (size_t)Mm * Cc;            // 1.024 MB

  // att background zeroed in-kernel (block-exclusive slices, fire-and-forget under
  // the raw barriers). R5-vs-R6 totals showed in-kernel wins over memset by ~28us.
  wcvt_kernel<<<(Mm * Cc + 255) / 256, 256, 0, stream>>>(w, whi, wlo);
  fused_mem_kernel<<<Tt / TB, 512, 0, stream>>>(x, w, whi, wlo, y_out, att_out);
}

// Round 10
// 559.833 us; speedup vs baseline: 1.4535x; 1.0988x over previous
//
#include <hip/hip_runtime.h>

typedef _Float16 f16x8 __attribute__((ext_vector_type(8)));
typedef float    f32x4 __attribute__((ext_vector_type(4)));

constexpr int Nn = 32, Cc = 256, HW = 1024, Mm = 2000, Tt = 32768;
constexpr int TB = 32;        // tokens per block (2 token-groups x 16)
constexpr int XROW = 264;     // X row stride (f16): 528 B rows, 16B-aligned rows
constexpr int YROW = 257;     // y accum row stride (fp32)
constexpr int LCAP = 512;     // candidate cap (expected ~218/block, +20 sigma)
constexpr int NT = 63;        // M tiles of 32 rows (62 full + 16-row tail)
constexpr float LAMBDA = 0.0025f;
constexpr float PLO = LAMBDA * (1.0f - 3e-3f);   // borderline window (covers GEMM noise + Z regroup)
constexpr float PHI = LAMBDA * (1.0f + 3e-3f);
constexpr float ECUT = 4.8f;  // candidate cut (per-logit e bits unchanged -> same set)
constexpr float SCL = 4096.0f, ISCL = 1.0f / 4096.0f;

__global__ void wcvt_kernel(const float* __restrict__ w,
                            _Float16* __restrict__ whi, _Float16* __restrict__ wlo) {
  int i = blockIdx.x * 256 + threadIdx.x;
  if (i < Mm * Cc) {
    float v = w[i];
    _Float16 h = (_Float16)v;
    whi[i] = h;
    wlo[i] = (_Float16)((v - (float)h) * SCL);
  }
}

// R9 post-mortem: spill fixed (FETCH 114->82MB) yet time unchanged -- and correct
// per-round normalization (R2 had 8 blocks/CU, not 2: 1.55k cy/tile, ~48cy/gl_lds)
// shows the GEMM floor is INVARIANT ~330-375us across all transports (R2 16MB/CU
// staged = R9 4MB/CU). All pipes <15%. The constant: 1 resident block/CU, 8 waves
// barrier-locked -> any stall idles the whole CU (no m114 overlap possible).
// R10: CO-RESIDENCY. 256-thread blocks (2 tg x 2 mh waves, R2's verified geometry:
// A-frags 64 regs, peak ~165 regs, fits (256,2)), TB=32, 32-row tiles, LDS 72.3KB
// -> 2 blocks/CU. Identical per-wave instruction mix to R9; only residency changes.
// Transport keeps R9's spill-free reg-staging + raw-barrier (lgkm-only) discipline.
__global__ __launch_bounds__(256, 2)
void fused_mem_kernel(const float* __restrict__ x, const float* __restrict__ wgt,
                      const _Float16* __restrict__ whi, const _Float16* __restrict__ wlo,
                      float* __restrict__ y_out, float* __restrict__ att_out) {
  // region: X stage f16[32][264] x2 = 33792 B -> B dbuf 2x32768 B -> yL f32[32][257]
  __shared__ __align__(16) float bufB[16384];       // 65536 B
  __shared__ int   lm[LCAP];
  __shared__ float le[LCAP];
  __shared__ float la[LCAP];
  __shared__ float Zred[64];
  __shared__ float invZ[TB];
  __shared__ float l1s[TB];
  __shared__ float dens[TB];
  __shared__ int   lcnt;
  _Float16* Xh = (_Float16*)bufB;
  _Float16* Xl = Xh + TB * XROW;
  float*    yL = bufB;
  char*     Bb = (char*)bufB;

  const int tid = threadIdx.x;
  const int wv  = tid >> 6;                 // 0..3
  const int l   = tid & 63;
  const int qw  = l >> 4;
  const int lr  = l & 15;
  const int tg  = wv & 1;                   // token group (16 tokens)
  const int mh  = wv >> 1;                  // M half within 32-row tile
  const int t0  = blockIdx.x * TB;
  const int n   = t0 >> 10;
  const int hw0 = t0 & 1023;

  if (tid == 0) lcnt = 0;
  if (tid < TB) l1s[tid] = 0.f;

  // ---- phase 1: X tile (32 tokens x 256 c) -> LDS f16 hi/lo ----
  {
    const int h = tid & 31, cb = tid >> 5;
    const float* xp = x + ((size_t)n * Cc) * HW + hw0 + h;
    #pragma unroll
    for (int j = 0; j < 32; ++j) {
      int c = cb * 32 + j;
      float v = xp[(size_t)c * HW];          // 32 lanes consecutive: 128B chunks
      _Float16 hh = (_Float16)v;
      Xh[h * XROW + c] = hh;
      Xl[h * XROW + c] = (_Float16)((v - (float)hh) * SCL);
    }
  }
  __syncthreads();                                  // B1

  // A fragments (this wave's 16 tokens); contents/layout = R2-verified mapping.
  f16x8 ahi[8], alo[8];
  #pragma unroll
  for (int ks = 0; ks < 8; ++ks) {
    const int r0 = (tg * 16 + lr) * XROW + ks * 32 + qw * 8;
    ahi[ks] = *(const f16x8*)&Xh[r0];
    alo[ks] = *(const f16x8*)&Xl[r0];
  }
  __syncthreads();                                  // B1b: X region now free -> B dbuf

  // B staging, reg-staged (spill-free R9 pattern): global float4 -> rs[8] ->
  // ds_write_b128, LDW/WRW adjacent (rs live ~8 instrs). Pre-swizzled source
  // (chunk ^= row&7), linear LDS dest; swizzled ds_read matches.
  float4 rs[8];
#define LDW(TILE) do {                                                        \
    _Pragma("unroll")                                                         \
    for (int i_ = 0; i_ < 8; ++i_) {                                          \
      const int u2_ = i_ * 256 + wv * 64 + l;      /* 0..2047 */              \
      const int r32_ = (u2_ >> 5) & 31;                                       \
      const int ck_ = u2_ & 31;                                               \
      int mr_ = (TILE) * 32 + r32_; mr_ = mr_ < Mm ? mr_ : (Mm - 1);          \
      const char* s_ = (const char*)(i_ < 4 ? whi : wlo)                      \
                     + (size_t)mr_ * 512 + ((ck_ ^ (r32_ & 7)) << 4);         \
      rs[i_] = *(const float4*)s_;                                            \
    }                                                                         \
  } while (0)
#define WRW(B) do {                                                           \
    char* b_ = Bb + (B) * 32768;                                              \
    _Pragma("unroll")                                                         \
    for (int i_ = 0; i_ < 8; ++i_) {                                          \
      const int u2_ = i_ * 256 + wv * 64 + l;                                 \
      *(float4*)(b_ + u2_ * 16) = rs[i_];                                     \
    }                                                                         \
  } while (0)

  // prologue: tile0 -> buf0
  LDW(0);
  WRW(0);
  asm volatile("s_waitcnt lgkmcnt(0)" ::: "memory");
  __builtin_amdgcn_s_barrier();                     // buf0 published (no vmcnt drain)

  float zp[4] = {0.f, 0.f, 0.f, 0.f};
  const int rrow = mh * 16 + lr;                    // W row within 32-row tile
  const int rsw  = rrow & 7;
  int cur = 0;
  for (int t = 0; t < NT; ++t) {
    // att background zeroing: fire-and-forget (raw barrier waits lgkm only);
    // fully drained at B2 before survivor writes. 128B contiguous per m-row.
    {
      int m = t * 32 + (tid >> 3);
      if (m < Mm) {
        f32x4 z4 = {0.f, 0.f, 0.f, 0.f};
        *(f32x4*)(att_out + ((size_t)(n * Mm + m)) * HW + hw0 + ((tid & 7) << 2)) = z4;
      }
    }

    if (t < NT - 1 || mh == 0) {                    // tail tile: 16 valid rows (mh==0 only)
      const char* bb = Bb + cur * 32768;
      f32x4 ahh = {0.f,0.f,0.f,0.f}, axl = {0.f,0.f,0.f,0.f}, alh = {0.f,0.f,0.f,0.f};
      #pragma unroll
      for (int kc = 0; kc < 2; ++kc) {              // B live range = 4 ks (32 regs)
        f16x8 bh[4], bl[4];
        #pragma unroll
        for (int k4 = 0; k4 < 4; ++k4) {
          const int ks = kc * 4 + k4;
          const int ch = rrow * 512 + (((ks * 4 + qw) ^ rsw) << 4);
          bh[k4] = *(const f16x8*)(bb + ch);
          bl[k4] = *(const f16x8*)(bb + 16384 + ch);
        }
        #pragma unroll
        for (int k4 = 0; k4 < 4; ++k4) {
          const int ks = kc * 4 + k4;
          ahh = __builtin_amdgcn_mfma_f32_16x16x32_f16(ahi[ks], bh[k4], ahh, 0, 0, 0);
          axl = __builtin_amdgcn_mfma_f32_16x16x32_f16(ahi[ks], bl[k4], axl, 0, 0, 0);
          alh = __builtin_amdgcn_mfma_f32_16x16x32_f16(alo[ks], bh[k4], alh, 0, 0, 0);
        }
      }
      const int mrow_ = t * 32 + rrow;
      #pragma unroll
      for (int r = 0; r < 4; ++r) {
        float s = fmaf(axl[r] + alh[r], ISCL, ahh[r]);   // logit, bit-identical chains
        float e = __expf(s);
        zp[r] += e;
        if (e > ECUT) {                                  // ~0.3% taken
          int slot = atomicAdd(&lcnt, 1);
          if (slot < LCAP) { lm[slot] = ((tg * 16 + qw * 4 + r) << 16) | mrow_; le[slot] = e; }
        }
      }
    }

    __builtin_amdgcn_sched_barrier(0);              // staging stays BELOW compute (no hoist)
    if (t + 1 < NT) {
      LDW(t + 1);                                   // adjacent load+write: rs live ~8 instrs
      WRW(cur ^ 1);                                 // graduated vmcnt waits (L2-resident W)
    }
    asm volatile("s_waitcnt lgkmcnt(0)" ::: "memory");   // ds_writes visible to all waves
    __builtin_amdgcn_s_barrier();                   // NO vmcnt drain: att stores stay in flight
    cur ^= 1;
  }
#undef LDW
#undef WRW

  #pragma unroll
  for (int o = 1; o < 16; o <<= 1)
    #pragma unroll
    for (int r = 0; r < 4; ++r) zp[r] += __shfl_xor(zp[r], o);
  if (lr == 0) {
    #pragma unroll
    for (int r = 0; r < 4; ++r)
      Zred[mh * 32 + tg * 16 + qw * 4 + r] = zp[r];
  }
  __syncthreads();                                  // B2 (full drain: att zero-stores land here)

  if (tid < TB) invZ[tid] = 1.f / (Zred[tid] + Zred[32 + tid]);
  __syncthreads();                                  // B3

  // ---- phase 4: candidate scan (exact fp32 recompute of borderline) + L1 ----
  const int ne = min(lcnt, LCAP);
  for (int e = tid; e < ne; e += 256) {
    const int tm = lm[e];
    const int t = tm >> 16, m = tm & 0xFFFF;
    float p = le[e] * invZ[t];
    float a = 0.f;
    if (p > PLO) {
      float pu = p;
      if (p < PHI) {
        // borderline (~few per block): exact fp32 dot from global x, W
        const float* xr = x + ((size_t)n * Cc) * HW + hw0 + t;
        const float* wr = wgt + (size_t)m * Cc;
        float s = 0.f;
        for (int c = 0; c < Cc; ++c) s = fmaf(xr[(size_t)c * HW], wr[c], s);
        pu = expf(s) * invZ[t];
      }
      float d = pu - LAMBDA;
      if (d > 0.f) {
        a = (d * pu) / (d + 1e-12f);
        atomicAdd(&l1s[t], a);
      }
    }
    la[e] = a;
  }
  __syncthreads();                                  // B4

  if (tid < TB) dens[tid] = fmaxf(l1s[tid], 1e-12f);
  for (int i = tid; i < TB * YROW; i += 256) yL[i] = 0.f;   // B dbuf dead; alias reuse
  __syncthreads();                                  // B5

  // ---- phase 6: sparse GEMM2 from survivor list (fp32 W) + att scatter ----
  // y accum layout PERMUTED: channel c lives at t*YROW + ((c&3)<<6 | c>>2) so the
  // atomics have 4B lane stride (2 lanes/bank = free).
  for (int e = wv; e < ne; e += 4) {                // wave-uniform entry -> no divergence
    float av = la[e];
    if (av > 0.f) {
      const int tm = lm[e];
      const int t = tm >> 16, m = tm & 0xFFFF;
      const float a = av / dens[t];
      float4 wf = *(const float4*)(wgt + (size_t)m * Cc + l * 4);   // c = 4l+i
      float* yr = yL + t * YROW + l;                // acc idx of c=4l+i is (i<<6)+l
      atomicAdd(yr + 0,   a * wf.x);
      atomicAdd(yr + 64,  a * wf.y);
      atomicAdd(yr + 128, a * wf.z);
      atomicAdd(yr + 192, a * wf.w);
      if (l == 0)
        att_out[((size_t)(n * Mm + m)) * HW + hw0 + t] = a;   // bg zeroed in-loop above
    }
  }
  __syncthreads();                                  // B6

  // ---- phase 7: y write (128B chunks: 32 consecutive hw per c); un-permute accum ----
  {
    const int h = tid & 31, cb = tid >> 5;
    float* yp = y_out + ((size_t)n * Cc) * HW + hw0 + h;
    #pragma unroll
    for (int j = 0; j < 32; ++j) {
      int c = cb * 32 + j;
      yp[(size_t)c * HW] = yL[h * YROW + (((c & 3) << 6) | (c >> 2))];
    }
  }
}

extern "C" void kernel_launch(void* const* d_in, const int* in_sizes, int n_in,
                              void* d_out, int out_size, void* d_ws, size_t ws_size,
                              hipStream_t stream) {
  const float* x = (const float*)d_in[0];
  const float* w = (const float*)d_in[1];
  float* y_out   = (float*)d_out;
  float* att_out = y_out + (size_t)Nn * Cc * HW;
  _Float16* whi = (_Float16*)d_ws;                  // 1.024 MB
  _Float16* wlo = whi + (size_t)Mm * Cc;            // 1.024 MB

  // att background zeroed in-kernel (block-exclusive slices, fire-and-forget under
  // the raw barriers; drained at B2 before survivor writes).
  wcvt_kernel<<<(Mm * Cc + 255) / 256, 256, 0, stream>>>(w, whi, wlo);
  fused_mem_kernel<<<Tt / TB, 256, 0, stream>>>(x, w, whi, wlo, y_out, att_out);
}